// Round 1
// baseline (867.339 us; speedup 1.0000x reference)
//
#include <hip/hip_runtime.h>
#include <hip/hip_bf16.h>

// BasicBlock (conv3x3+BN+ReLU, conv3x3+BN, +identity, ReLU) via implicit-GEMM
// bf16 MFMA. N=32, C=256, H=W=56, fp32 I/O, bf16 internal compute.
//
// GEMM view per conv: C[co][p] = sum_k W[co][k] * Patch[k][p],
//   k = ci*9 + (kh*3+kw)  (matches w[co][ci][3][3] memory layout exactly)
//   p = flattened spatial within image (3136 = 49 tiles of 64)
// Block tile: BM=256 (all co) x BN=64 spatial, BK=32, 8 waves (4Mx2N),
// per-wave 64x32 via 4x2 fragments of v_mfma_f32_16x16x32_bf16.

typedef __attribute__((ext_vector_type(8))) short bf16x8;
typedef __attribute__((ext_vector_type(4))) float f32x4;

#define C_CH   256
#define HW_IMG 3136     // 56*56
#define KTOT   2304     // 256*9
#define WELEM  589824   // 256*2304
#define BN_T   64
#define BK     32
#define NK     72       // 2304/32
#define LSTR   40       // LDS row stride (bf16 elems) = 80B: 16B-aligned, 2-way banks

__device__ __forceinline__ ushort f2bf(float f) {
    __hip_bfloat16 h = __float2bfloat16(f);
    return *reinterpret_cast<ushort*>(&h);
}

__global__ void prep_kernel(const float* __restrict__ w1, const float* __restrict__ w2,
                            const float* __restrict__ g1, const float* __restrict__ b1,
                            const float* __restrict__ m1, const float* __restrict__ v1,
                            const float* __restrict__ g2, const float* __restrict__ b2,
                            const float* __restrict__ m2, const float* __restrict__ v2,
                            ushort* __restrict__ wb1, ushort* __restrict__ wb2,
                            float* __restrict__ bn) {
    int gid = blockIdx.x * 256 + threadIdx.x;
    if (gid < WELEM) wb1[gid] = f2bf(w1[gid]);
    int g2i = gid - WELEM;
    if (g2i >= 0 && g2i < WELEM) wb2[g2i] = f2bf(w2[g2i]);
    if (gid < C_CH) {
        float i1 = g1[gid] * rsqrtf(v1[gid] + 1e-5f);
        bn[gid]          = i1;
        bn[C_CH + gid]   = b1[gid] - m1[gid] * i1;
        float i2 = g2[gid] * rsqrtf(v2[gid] + 1e-5f);
        bn[2*C_CH + gid] = i2;
        bn[3*C_CH + gid] = b2[gid] - m2[gid] * i2;
    }
}

template<bool SECOND>
__global__ __launch_bounds__(512) void conv_kernel(
    const void* __restrict__ src_v, const ushort* __restrict__ wb,
    const float* __restrict__ bninv, const float* __restrict__ bnadd,
    const float* __restrict__ ident, void* __restrict__ dst_v)
{
    __shared__ ushort Alds[2][256 * LSTR];  // 2*256*40*2B = 40960 B
    __shared__ ushort Blds[2][BN_T * LSTR]; // 2* 64*40*2B = 10240 B

    const int tid = threadIdx.x;
    const int w  = tid >> 6;       // wave 0..7
    const int l  = tid & 63;
    const int wm = w & 3;          // wave row (4 waves in M)
    const int wn = w >> 2;         // wave col (2 waves in N)
    const int lr = l & 15;
    const int lg = l >> 4;

    const int tile = blockIdx.x;   // 0..1567
    const int n    = tile / 49;
    const int p0i  = (tile - n * 49) * 64;
    const int pi   = p0i + l;      // this lane's spatial gather position
    const int h    = pi / 56;
    const int wc   = pi - h * 56;

    const float*  xs = (const float*)src_v  + (size_t)n * (C_CH * HW_IMG);
    const ushort* ys = (const ushort*)src_v + (size_t)n * (C_CH * HW_IMG);

    f32x4 acc[4][2];
#pragma unroll
    for (int mr = 0; mr < 4; ++mr)
#pragma unroll
        for (int nc = 0; nc < 2; ++nc) {
            f32x4 z = {0.f, 0.f, 0.f, 0.f};
            acc[mr][nc] = z;
        }

    bf16x8 areg[2];
    float  bregf[4];
    ushort bregh[4];

    auto load_stage = [&](int kk) {
        // A: weights, bf16, rows contiguous in k. 512 thr x 2 x 16B = 16KB tile.
#pragma unroll
        for (int it = 0; it < 2; ++it) {
            int row = (tid >> 2) + it * 128;
            int seg = tid & 3;
            areg[it] = *(const bf16x8*)(wb + (size_t)row * KTOT + kk * BK + seg * 8);
        }
        // B: gather 4 taps per thread; k wave-uniform per j, p = lane (coalesced).
#pragma unroll
        for (int j = 0; j < 4; ++j) {
            int k  = kk * BK + (w << 2) + j;
            int ci = k / 9;
            int r  = k - ci * 9;
            int kh = r / 3;
            int dh = kh - 1;
            int dw = (r - kh * 3) - 1;
            int hh = h + dh, ww = wc + dw;
            bool ok = ((unsigned)hh < 56u) && ((unsigned)ww < 56u);
            int off = ci * HW_IMG + hh * 56 + ww;
            if constexpr (SECOND) {
                bregh[j] = ok ? ys[off] : (ushort)0;
            } else {
                bregf[j] = ok ? xs[off] : 0.f;
            }
        }
    };

    auto write_stage = [&](int buf) {
#pragma unroll
        for (int it = 0; it < 2; ++it) {
            int row = (tid >> 2) + it * 128;
            int seg = tid & 3;
            *(bf16x8*)&Alds[buf][row * LSTR + seg * 8] = areg[it];
        }
        ushort u0, u1, u2, u3;
        if constexpr (SECOND) {
            u0 = bregh[0]; u1 = bregh[1]; u2 = bregh[2]; u3 = bregh[3];
        } else {
            u0 = f2bf(bregf[0]); u1 = f2bf(bregf[1]);
            u2 = f2bf(bregf[2]); u3 = f2bf(bregf[3]);
        }
        uint2 pk;
        pk.x = (uint)u0 | ((uint)u1 << 16);
        pk.y = (uint)u2 | ((uint)u3 << 16);
        *(uint2*)&Blds[buf][l * LSTR + (w << 2)] = pk;  // Blds[p][k], transposed for frag reads
    };

    auto compute = [&](int buf) {
        bf16x8 af[4], bfr[2];
#pragma unroll
        for (int mr = 0; mr < 4; ++mr)
            af[mr] = *(const bf16x8*)&Alds[buf][(wm * 64 + mr * 16 + lr) * LSTR + lg * 8];
#pragma unroll
        for (int nc = 0; nc < 2; ++nc)
            bfr[nc] = *(const bf16x8*)&Blds[buf][(wn * 32 + nc * 16 + lr) * LSTR + lg * 8];
#pragma unroll
        for (int mr = 0; mr < 4; ++mr)
#pragma unroll
            for (int nc = 0; nc < 2; ++nc)
                acc[mr][nc] = __builtin_amdgcn_mfma_f32_16x16x32_bf16(
                    af[mr], bfr[nc], acc[mr][nc], 0, 0, 0);
    };

    load_stage(0);
    write_stage(0);
    __syncthreads();

    for (int kk = 0; kk < NK; ++kk) {
        const int cur = kk & 1;
        if (kk + 1 < NK) load_stage(kk + 1);   // global loads in flight during compute
        compute(cur);
        __syncthreads();
        if (kk + 1 < NK) write_stage(cur ^ 1);
        __syncthreads();
    }

    // Epilogue: BN (+identity) (+ReLU). C/D layout: col=lane&15, row=(lane>>4)*4+i.
    const size_t nbase = (size_t)n * (C_CH * HW_IMG);
#pragma unroll
    for (int mr = 0; mr < 4; ++mr) {
#pragma unroll
        for (int nc = 0; nc < 2; ++nc) {
            int pcol = p0i + wn * 32 + nc * 16 + lr;
#pragma unroll
            for (int i = 0; i < 4; ++i) {
                int co = wm * 64 + mr * 16 + lg * 4 + i;
                float val = acc[mr][nc][i] * bninv[co] + bnadd[co];
                size_t oidx = nbase + (size_t)co * HW_IMG + pcol;
                if constexpr (SECOND) {
                    val += ident[oidx];
                    ((float*)dst_v)[oidx] = fmaxf(val, 0.f);
                } else {
                    ((ushort*)dst_v)[oidx] = f2bf(fmaxf(val, 0.f));
                }
            }
        }
    }
}

extern "C" void kernel_launch(void* const* d_in, const int* in_sizes, int n_in,
                              void* d_out, int out_size, void* d_ws, size_t ws_size,
                              hipStream_t stream) {
    const float* x  = (const float*)d_in[0];
    const float* w1 = (const float*)d_in[1];
    const float* g1 = (const float*)d_in[2];
    const float* b1 = (const float*)d_in[3];
    const float* m1 = (const float*)d_in[4];
    const float* v1 = (const float*)d_in[5];
    const float* w2 = (const float*)d_in[6];
    const float* g2 = (const float*)d_in[7];
    const float* b2 = (const float*)d_in[8];
    const float* m2 = (const float*)d_in[9];
    const float* v2 = (const float*)d_in[10];

    // ws layout: wb1 (1.18MB bf16) | wb2 (1.18MB) | bn params (4KB f32) | y (51.4MB bf16)
    ushort* wb1 = (ushort*)d_ws;
    ushort* wb2 = wb1 + WELEM;
    float*  bn  = (float*)(wb2 + WELEM);
    ushort* y   = (ushort*)(bn + 4 * C_CH);

    prep_kernel<<<dim3((2 * WELEM + 255) / 256), dim3(256), 0, stream>>>(
        w1, w2, g1, b1, m1, v1, g2, b2, m2, v2, wb1, wb2, bn);

    conv_kernel<false><<<dim3(1568), dim3(512), 0, stream>>>(
        (const void*)x, wb1, bn, bn + 256, (const float*)nullptr, (void*)y);

    conv_kernel<true><<<dim3(1568), dim3(512), 0, stream>>>(
        (const void*)y, wb2, bn + 512, bn + 768, x, d_out);
}

// Round 2
// 671.657 us; speedup vs baseline: 1.2913x; 1.2913x over previous
//
#include <hip/hip_runtime.h>
#include <hip/hip_bf16.h>
#include <type_traits>

// BasicBlock via implicit-GEMM bf16 MFMA, tap-major K ordering.
// k' = r*256 + ci  (tap-major) -> within a BK=32 step the tap r is fixed:
// B-gather is 8 stride-HW loads with a precomputed border mask, no decode.
// Weights repacked to [co][r][ci] so A fragments are contiguous 16B/lane and
// are loaded DIRECTLY global->VGPR (L2-resident, no LDS staging for A).
// Block: 256 thr (4 waves), tile 256co x 64p, per wave 64x64 (16 MFMA/step),
// ONE barrier per K-step, 2-step-deep B prefetch (reg ping-pong).

typedef __attribute__((ext_vector_type(8))) short bf16x8;
typedef __attribute__((ext_vector_type(4))) float f32x4;

#define C_CH   256
#define HW_IMG 3136
#define CHW    802816     // 256*3136
#define KTOT   2304       // 256*9
#define WELEM  589824     // 256*2304
#define BK     32
#define NK     72
#define LSTR   40         // LDS row stride (bf16): 80B, 16B-aligned, 2-way banks (free)

__device__ __forceinline__ ushort f2bf(float f) {
    union { __hip_bfloat16 h; ushort u; } cv;
    cv.h = __float2bfloat16(f);
    return cv.u;
}

__global__ void prep_kernel(const float* __restrict__ w1, const float* __restrict__ w2,
                            const float* __restrict__ g1, const float* __restrict__ b1,
                            const float* __restrict__ m1, const float* __restrict__ v1,
                            const float* __restrict__ g2, const float* __restrict__ b2,
                            const float* __restrict__ m2, const float* __restrict__ v2,
                            ushort* __restrict__ wb1, ushort* __restrict__ wb2,
                            float* __restrict__ bn) {
    int gid = blockIdx.x * 256 + threadIdx.x;
    if (gid < WELEM) {
        // dest index: co*2304 + r*256 + ci  <- src w[co][ci][r]
        int co  = gid / KTOT;
        int rem = gid - co * KTOT;
        int r   = rem >> 8;
        int ci  = rem & 255;
        wb1[gid] = f2bf(w1[(co * C_CH + ci) * 9 + r]);
    }
    int g2i = gid - WELEM;
    if (g2i >= 0 && g2i < WELEM) {
        int co  = g2i / KTOT;
        int rem = g2i - co * KTOT;
        int r   = rem >> 8;
        int ci  = rem & 255;
        wb2[g2i] = f2bf(w2[(co * C_CH + ci) * 9 + r]);
    }
    if (gid < C_CH) {
        float i1 = g1[gid] * rsqrtf(v1[gid] + 1e-5f);
        bn[gid]            = i1;
        bn[C_CH + gid]     = b1[gid] - m1[gid] * i1;
        float i2 = g2[gid] * rsqrtf(v2[gid] + 1e-5f);
        bn[2*C_CH + gid]   = i2;
        bn[3*C_CH + gid]   = b2[gid] - m2[gid] * i2;
    }
}

template<bool SECOND>
__global__ __launch_bounds__(256) void conv_kernel(
    const void* __restrict__ src_v, const ushort* __restrict__ wb,
    const float* __restrict__ bnp,      // [0,256): inv, [256,512): add
    const float* __restrict__ ident, void* __restrict__ dst_v)
{
    using SRC_T = std::conditional_t<SECOND, ushort, float>;
    const SRC_T* src = (const SRC_T*)src_v;

    __shared__ ushort Blds[2][64 * LSTR];   // 2*64*40*2B = 10240 B

    const int tid = threadIdx.x;
    const int wv  = tid >> 6;      // wave 0..3 -> co block
    const int l   = tid & 63;
    const int lr  = l & 15;
    const int lg  = l >> 4;

    const int tile = blockIdx.x;   // 0..1567
    const int n    = tile / 49;
    const int p0   = (tile - n * 49) * 64;

    // ---- staging role: thread = (pcol = l, cig = wv) covers ci cig*8..+7
    const int pcol = l;
    const int cig  = wv;
    const int p_st = p0 + pcol;
    const int h_st = p_st / 56;
    const int w_st = p_st - h_st * 56;
    unsigned mask = 0;
#pragma unroll
    for (int r = 0; r < 9; ++r) {
        int dh = r / 3 - 1, dw = r % 3 - 1;
        if ((unsigned)(h_st + dh) < 56u && (unsigned)(w_st + dw) < 56u)
            mask |= 1u << r;
    }
    const SRC_T* sb = src + (size_t)n * CHW;

    f32x4 acc[4][4];
#pragma unroll
    for (int mr = 0; mr < 4; ++mr)
#pragma unroll
        for (int nc = 0; nc < 4; ++nc) {
            f32x4 z = {0.f, 0.f, 0.f, 0.f};
            acc[mr][nc] = z;
        }

    bf16x8 a0[4], a1[4];
    SRC_T  sA[8], sB[8], st0[8];
    bool   okA, okB, ok0;

    auto stage = [&](int kk, SRC_T* sr, bool& okf) {
        int r   = kk >> 3;                 // tap, uniform
        int dh  = r / 3 - 1;
        int dwv = r - (r / 3) * 3 - 1;
        bool ok = (mask >> r) & 1u;
        okf = ok;
        int sbase = (h_st + dh) * 56 + (w_st + dwv);
        int ci0   = ((kk & 7) << 5) + (cig << 3);
        const SRC_T* p = sb + ci0 * HW_IMG + (ok ? sbase : 0);  // clamped: always in-bounds
#pragma unroll
        for (int j = 0; j < 8; ++j)
            sr[j] = p[j * HW_IMG];
    };

    auto writeB = [&](int buf, SRC_T* sr, bool ok) {
        uint u[8];
#pragma unroll
        for (int j = 0; j < 8; ++j) {
            ushort b;
            if constexpr (SECOND) b = sr[j]; else b = f2bf(sr[j]);
            u[j] = ok ? (uint)b : 0u;
        }
        uint4 pk;
        pk.x = u[0] | (u[1] << 16);
        pk.y = u[2] | (u[3] << 16);
        pk.z = u[4] | (u[5] << 16);
        pk.w = u[6] | (u[7] << 16);
        *(uint4*)&Blds[buf][pcol * LSTR + (cig << 3)] = pk;
    };

    auto loadA = [&](int kk, bf16x8* a) {
#pragma unroll
        for (int mr = 0; mr < 4; ++mr) {
            int co = (wv << 6) + (mr << 4) + lr;
            a[mr] = *(const bf16x8*)(wb + (size_t)co * KTOT + (kk << 5) + (lg << 3));
        }
    };

    auto compute = [&](int buf, bf16x8* a) {
        bf16x8 bfr[4];
#pragma unroll
        for (int nc = 0; nc < 4; ++nc)
            bfr[nc] = *(const bf16x8*)&Blds[buf][((nc << 4) + lr) * LSTR + (lg << 3)];
#pragma unroll
        for (int mr = 0; mr < 4; ++mr)
#pragma unroll
            for (int nc = 0; nc < 4; ++nc)
                acc[mr][nc] = __builtin_amdgcn_mfma_f32_16x16x32_bf16(
                    a[mr], bfr[nc], acc[mr][nc], 0, 0, 0);
    };

    // prologue
    stage(0, st0, ok0);
    writeB(0, st0, ok0);
    stage(1, sA, okA);
    loadA(0, a0);
    __syncthreads();

    for (int kk = 0; kk < NK; kk += 2) {
        // step kk (even): reads buf0, writes buf1 with data(kk+1) from sA
        if (kk + 2 < NK) stage(kk + 2, sB, okB);
        if (kk + 1 < NK) loadA(kk + 1, a1);
        compute(0, a0);
        if (kk + 1 < NK) writeB(1, sA, okA);
        __syncthreads();
        // step kk+1: reads buf1, writes buf0 with data(kk+2) from sB
        if (kk + 3 < NK) stage(kk + 3, sA, okA);
        if (kk + 2 < NK) loadA(kk + 2, a0);
        compute(1, a1);
        if (kk + 2 < NK) writeB(0, sB, okB);
        __syncthreads();
    }

    // epilogue: BN (+identity) (+ReLU). C/D: col=lane&15, row=(lane>>4)*4+i
    const size_t nbase = (size_t)n * CHW;
#pragma unroll
    for (int mr = 0; mr < 4; ++mr) {
#pragma unroll
        for (int nc = 0; nc < 4; ++nc) {
            int pc = p0 + (nc << 4) + lr;
#pragma unroll
            for (int i = 0; i < 4; ++i) {
                int co = (wv << 6) + (mr << 4) + (lg << 2) + i;
                float val = acc[mr][nc][i] * bnp[co] + bnp[C_CH + co];
                size_t o = nbase + (size_t)co * HW_IMG + pc;
                if constexpr (SECOND) {
                    val += ident[o];
                    ((float*)dst_v)[o] = fmaxf(val, 0.f);
                } else {
                    ((ushort*)dst_v)[o] = f2bf(fmaxf(val, 0.f));
                }
            }
        }
    }
}

extern "C" void kernel_launch(void* const* d_in, const int* in_sizes, int n_in,
                              void* d_out, int out_size, void* d_ws, size_t ws_size,
                              hipStream_t stream) {
    const float* x  = (const float*)d_in[0];
    const float* w1 = (const float*)d_in[1];
    const float* g1 = (const float*)d_in[2];
    const float* b1 = (const float*)d_in[3];
    const float* m1 = (const float*)d_in[4];
    const float* v1 = (const float*)d_in[5];
    const float* w2 = (const float*)d_in[6];
    const float* g2 = (const float*)d_in[7];
    const float* b2 = (const float*)d_in[8];
    const float* m2 = (const float*)d_in[9];
    const float* v2 = (const float*)d_in[10];

    ushort* wb1 = (ushort*)d_ws;
    ushort* wb2 = wb1 + WELEM;
    float*  bn  = (float*)(wb2 + WELEM);
    ushort* y   = (ushort*)(bn + 4 * C_CH);

    prep_kernel<<<dim3((2 * WELEM + 255) / 256), dim3(256), 0, stream>>>(
        w1, w2, g1, b1, m1, v1, g2, b2, m2, v2, wb1, wb2, bn);

    conv_kernel<false><<<dim3(1568), dim3(256), 0, stream>>>(
        (const void*)x, wb1, bn, x /*unused*/, (void*)y);

    conv_kernel<true><<<dim3(1568), dim3(256), 0, stream>>>(
        (const void*)y, wb2, bn + 512, x, d_out);
}

// Round 3
// 407.899 us; speedup vs baseline: 2.1264x; 1.6466x over previous
//
#include <hip/hip_runtime.h>
#include <hip/hip_bf16.h>

// BasicBlock via chunked shift-GEMM bf16 MFMA.
// conv3x3 = sum over 9 taps of GEMM(W_r, shift(X, off_r)). Per block:
// output tile 256co x 64p. ci processed in 4 chunks of 64; per chunk a
// 192-row spatial window [p0-64, p0+128) x 64ci is staged in LDS via
// global_load_lds (per-lane src addr, zero-buffer for out-of-image rows),
// then 18 K-steps (9 taps x BK=32x2) of pure ds_read+MFMA, NO barriers.
// 4 barriers total per kernel. Tap shifts = compile-time ds_read offsets.
// Sources are bf16 [n][p][ci] (xT precomputed into d_out scratch; yT from
// conv1's LDS-transposed epilogue). Weights frag-packed for coalesced L2.

typedef __attribute__((ext_vector_type(8))) short bf16x8;
typedef __attribute__((ext_vector_type(4))) float f32x4;
typedef __attribute__((ext_vector_type(4))) unsigned int uint4v;

#define C_CH   256
#define HW_IMG 3136
#define CHW    802816     // 256*3136
#define WELEM  589824     // 256*2304
#define WROWS  192        // staged window rows
#define RSTR   72         // LDS row stride in ushorts (64 data + 8 pad) = 144B
#define BUFE   13824      // WROWS*RSTR ushorts per buffer (27648B)
#define NWIN   27         // global_load_lds instrs per chunk (27*1024B)

__device__ __forceinline__ ushort f2bf(float f){
    union{__hip_bfloat16 h; ushort u;} c; c.h = __float2bfloat16(f); return c.u;
}

__global__ __launch_bounds__(256) void prep_kernel(
    const float* __restrict__ w1, const float* __restrict__ w2,
    const float* __restrict__ g1, const float* __restrict__ b1,
    const float* __restrict__ m1, const float* __restrict__ v1,
    const float* __restrict__ g2, const float* __restrict__ b2,
    const float* __restrict__ m2, const float* __restrict__ v2,
    ushort* __restrict__ wf1, ushort* __restrict__ wf2,
    float* __restrict__ bn, ushort* __restrict__ zb)
{
    int gid = blockIdx.x * 256 + threadIdx.x;
    // frag-packed weights: elem d -> j=d&7, l=(d>>3)&63, ct=(d>>9)&15, fb=d>>13
    // fb = r*8 + k32; logical co = ct*16+(l&15), ci = k32*32+(l>>4)*8+j, tap r
    if (gid < WELEM) {
        int j = gid & 7, l = (gid >> 3) & 63, ct = (gid >> 9) & 15, fb = gid >> 13;
        int k32 = fb & 7, r = fb >> 3;
        int co = ct * 16 + (l & 15);
        int ci = k32 * 32 + (l >> 4) * 8 + j;
        wf1[gid] = f2bf(w1[(co * C_CH + ci) * 9 + r]);
    }
    int g2i = gid - WELEM;
    if (g2i >= 0 && g2i < WELEM) {
        int j = g2i & 7, l = (g2i >> 3) & 63, ct = (g2i >> 9) & 15, fb = g2i >> 13;
        int k32 = fb & 7, r = fb >> 3;
        int co = ct * 16 + (l & 15);
        int ci = k32 * 32 + (l >> 4) * 8 + j;
        wf2[g2i] = f2bf(w2[(co * C_CH + ci) * 9 + r]);
    }
    if (gid < C_CH) {
        float i1 = g1[gid] * rsqrtf(v1[gid] + 1e-5f);
        bn[gid]            = i1;
        bn[C_CH + gid]     = b1[gid] - m1[gid] * i1;
        float i2 = g2[gid] * rsqrtf(v2[gid] + 1e-5f);
        bn[2*C_CH + gid]   = i2;
        bn[3*C_CH + gid]   = b2[gid] - m2[gid] * i2;
    }
    if (gid < 512) zb[gid] = 0;
}

// x [n][ci][p] f32 -> xT [n][p][ci] bf16. 64ci x 64p tile per block.
__global__ __launch_bounds__(256) void xpose_kernel(
    const float* __restrict__ x, ushort* __restrict__ xT)
{
    __shared__ ushort T[64 * RSTR];
    int tid = threadIdx.x;
    int b = blockIdx.x;                  // 32*49*4
    int n = b / 196, rem = b % 196;
    int pb = rem >> 2, cb = rem & 3;
    int lane = tid & 63, cr = tid >> 6;
    const float* xp = x + ((size_t)(n * C_CH + cb * 64)) * HW_IMG + pb * 64 + lane;
#pragma unroll
    for (int j = 0; j < 16; ++j) {
        int cil = cr * 16 + j;
        T[lane * RSTR + cil] = f2bf(xp[(size_t)cil * HW_IMG]);
    }
    __syncthreads();
#pragma unroll
    for (int it = 0; it < 2; ++it) {
        int slot = it * 256 + tid;       // 512 slots = 64 rows x 8 granules
        int p = slot >> 3, g = slot & 7;
        uint4v v = *(const uint4v*)&T[p * RSTR + g * 8];
        *(uint4v*)(xT + ((size_t)n * HW_IMG + pb * 64 + p) * C_CH + cb * 64 + g * 8) = v;
    }
}

template<bool SECOND>
__global__ __launch_bounds__(256, 2) void conv_kernel(
    const ushort* __restrict__ srcT,    // [n][p][ci] bf16
    const ushort* __restrict__ wf,      // frag-packed weights
    const float* __restrict__ bnp,      // inv | add
    const float* __restrict__ ident,    // x fp32 (conv2)
    const ushort* __restrict__ zb,
    void* __restrict__ dst)
{
    __shared__ ushort B[2 * BUFE];      // 55296 B

    const int tid = threadIdx.x;
    const int wv = tid >> 6, l = tid & 63;
    const int lr = l & 15, lg = l >> 4;

    int bid = blockIdx.x;
    int swz = (bid & 7) * 196 + (bid >> 3);   // XCD-chunked, bijective (1568=8*196)
    const int n = swz / 49, pt = swz % 49;
    const int p0 = pt * 64;

    // W-border masks per nc (lane's output p = p0 + nc*16 + lr)
    bool wLa[4], wRa[4];
    int vbe[4];
#pragma unroll
    for (int nc = 0; nc < 4; ++nc) {
        int p = p0 + nc * 16 + lr;
        int w = p % 56;
        wLa[nc] = (w > 0);
        wRa[nc] = (w < 55);
        vbe[nc] = (nc * 16 + lr) * RSTR + lg * 8;   // B-frag LDS base (ushort idx)
    }

    // staging source addresses (chunk-0 ci base); invalid rows -> zero buffer
    const ushort* sA[7];
#pragma unroll
    for (int ii = 0; ii < 7; ++ii) {
        int inst = wv + ii * 4;
        int idx = inst * 1024 + l * 16;          // byte within window image
        int row = idx / 144;
        int g = (idx % 144) >> 4;                // 0..8 (8 = pad granule)
        int gp = p0 - 64 + row;
        bool val = (g < 8) && (gp >= 0) && (gp < HW_IMG);
        sA[ii] = val ? (srcT + ((size_t)n * HW_IMG + gp) * C_CH + g * 8)
                     : (zb + g * 8);
    }

    auto stage = [&](int cix, int bufE) {
#pragma unroll
        for (int ii = 0; ii < 7; ++ii) {
            int inst = wv + ii * 4;
            if (inst < NWIN) {
                __builtin_amdgcn_global_load_lds(
                    (const __attribute__((address_space(1))) void*)(sA[ii] + cix * 64),
                    (__attribute__((address_space(3))) void*)&B[bufE + inst * 512],
                    16, 0, 0);
            }
        }
    };

    f32x4 acc[4][4];
#pragma unroll
    for (int mr = 0; mr < 4; ++mr)
#pragma unroll
        for (int nc = 0; nc < 4; ++nc) {
            f32x4 z = {0.f, 0.f, 0.f, 0.f};
            acc[mr][nc] = z;
        }
    const bf16x8 z8 = {0,0,0,0,0,0,0,0};

    auto doChunk = [&](int cix, int bufE) {
        const ushort* pW = wf + (size_t)cix * 16384 + wv * 2048 + l * 8;
#pragma unroll
        for (int r = 0; r < 9; ++r) {
            const int dh = r / 3 - 1, dw = r % 3 - 1;
            const int off = dh * 56 + dw;
#pragma unroll
            for (int ks = 0; ks < 2; ++ks) {
                bf16x8 a[4], bq[4];
#pragma unroll
                for (int mr = 0; mr < 4; ++mr)
                    a[mr] = *(const bf16x8*)(pW + (r * 8 + ks) * 8192 + mr * 512);
#pragma unroll
                for (int nc = 0; nc < 4; ++nc) {
                    bq[nc] = *(const bf16x8*)&B[vbe[nc] + bufE + (64 + off) * RSTR + ks * 32];
                    if (dw == -1) bq[nc] = wLa[nc] ? bq[nc] : z8;
                    if (dw ==  1) bq[nc] = wRa[nc] ? bq[nc] : z8;
                }
#pragma unroll
                for (int mr = 0; mr < 4; ++mr)
#pragma unroll
                    for (int nc = 0; nc < 4; ++nc)
                        acc[mr][nc] = __builtin_amdgcn_mfma_f32_16x16x32_bf16(
                            a[mr], bq[nc], acc[mr][nc], 0, 0, 0);
            }
        }
    };

    stage(0, 0);
    __syncthreads();
    stage(1, BUFE);  doChunk(0, 0);     __syncthreads();
    stage(2, 0);     doChunk(1, BUFE);  __syncthreads();
    stage(3, BUFE);  doChunk(2, 0);     __syncthreads();
                     doChunk(3, BUFE);
    __syncthreads();

    if constexpr (!SECOND) {
        // epilogue: BN+ReLU, LDS-transpose to yT [n][p][co] bf16
        ushort* T = B;                  // reuse: [64 p][264] (256 co + 8 pad)
#pragma unroll
        for (int mr = 0; mr < 4; ++mr) {
#pragma unroll
            for (int nc = 0; nc < 4; ++nc) {
                int co0 = wv * 64 + mr * 16 + lg * 4;
                float v0 = fmaxf(acc[mr][nc][0] * bnp[co0+0] + bnp[C_CH+co0+0], 0.f);
                float v1 = fmaxf(acc[mr][nc][1] * bnp[co0+1] + bnp[C_CH+co0+1], 0.f);
                float v2 = fmaxf(acc[mr][nc][2] * bnp[co0+2] + bnp[C_CH+co0+2], 0.f);
                float v3 = fmaxf(acc[mr][nc][3] * bnp[co0+3] + bnp[C_CH+co0+3], 0.f);
                uint2 pk;
                pk.x = (uint)f2bf(v0) | ((uint)f2bf(v1) << 16);
                pk.y = (uint)f2bf(v2) | ((uint)f2bf(v3) << 16);
                *(uint2*)&T[(nc * 16 + lr) * 264 + co0] = pk;
            }
        }
        __syncthreads();
        ushort* yT = (ushort*)dst;
#pragma unroll
        for (int it = 0; it < 8; ++it) {
            int slot = it * 256 + tid;  // 2048 slots = 64 rows x 32 granules
            int row = slot >> 5, g = slot & 31;
            uint4v v = *(const uint4v*)&T[row * 264 + g * 8];
            *(uint4v*)(yT + ((size_t)n * HW_IMG + p0 + row) * C_CH + g * 8) = v;
        }
    } else {
        // epilogue: BN + identity + ReLU, fp32 out [n][co][p]
        const size_t nbase = (size_t)n * CHW;
        float* out = (float*)dst;
#pragma unroll
        for (int mr = 0; mr < 4; ++mr) {
#pragma unroll
            for (int nc = 0; nc < 4; ++nc) {
                int pc = p0 + nc * 16 + lr;
#pragma unroll
                for (int i = 0; i < 4; ++i) {
                    int co = wv * 64 + mr * 16 + lg * 4 + i;
                    size_t o = nbase + (size_t)co * HW_IMG + pc;
                    float val = acc[mr][nc][i] * bnp[co] + bnp[C_CH + co] + ident[o];
                    out[o] = fmaxf(val, 0.f);
                }
            }
        }
    }
}

extern "C" void kernel_launch(void* const* d_in, const int* in_sizes, int n_in,
                              void* d_out, int out_size, void* d_ws, size_t ws_size,
                              hipStream_t stream) {
    const float* x  = (const float*)d_in[0];
    const float* w1 = (const float*)d_in[1];
    const float* g1 = (const float*)d_in[2];
    const float* b1 = (const float*)d_in[3];
    const float* m1 = (const float*)d_in[4];
    const float* v1 = (const float*)d_in[5];
    const float* w2 = (const float*)d_in[6];
    const float* g2 = (const float*)d_in[7];
    const float* b2 = (const float*)d_in[8];
    const float* m2 = (const float*)d_in[9];
    const float* v2 = (const float*)d_in[10];

    // ws: wf1 | wf2 | bn(1024 f32) | zb(512 us) | yT(25.7M us)  ~= 54 MB
    ushort* wf1 = (ushort*)d_ws;
    ushort* wf2 = wf1 + WELEM;
    float*  bn  = (float*)(wf2 + WELEM);
    ushort* zb  = (ushort*)(bn + 4 * C_CH);
    ushort* yT  = zb + 512;
    // xT scratch lives in d_out (51.4MB bf16 <= 102.8MB fp32 buffer);
    // conv2 never reads xT and fully overwrites d_out.
    ushort* xT  = (ushort*)d_out;

    prep_kernel<<<dim3(4608), dim3(256), 0, stream>>>(
        w1, w2, g1, b1, m1, v1, g2, b2, m2, v2, wf1, wf2, bn, zb);

    xpose_kernel<<<dim3(6272), dim3(256), 0, stream>>>(x, xT);

    conv_kernel<false><<<dim3(1568), dim3(256), 0, stream>>>(
        xT, wf1, bn, x, zb, (void*)yT);

    conv_kernel<true><<<dim3(1568), dim3(256), 0, stream>>>(
        yT, wf2, bn + 512, x, zb, d_out);
}

// Round 4
// 382.034 us; speedup vs baseline: 2.2703x; 1.0677x over previous
//
#include <hip/hip_runtime.h>
#include <hip/hip_bf16.h>

// BasicBlock via chunked shift-GEMM bf16 MFMA, R3: depth-2 A-prefetch +
// conflict-free 80B LDS rows (ci-chunk 32).
// conv3x3 = sum over 9 taps of GEMM(W_r, shift(X, off_r)). Per block:
// output tile 256co x 64p; ci in 8 chunks of 32. Per chunk a 192-row
// spatial window [p0-64,p0+128) x 32ci staged in LDS (global_load_lds,
// linear dest = slot*16B since row*80+g*16 = slot*16), then 9 tap-steps of
// ds_read+MFMA. K loop flattened to 72 compile-time steps with A-frag
// loads issued 2 steps ahead into a 3-deep static register rotation.
// Row stride 80B -> ds_read_b128 slot = (5*row+lg) mod 8, bijective: zero
// bank conflicts. Weights frag-packed [chunk][tap][ct][lane][j] in prep.

typedef __attribute__((ext_vector_type(8))) short bf16x8;
typedef __attribute__((ext_vector_type(4))) float f32x4;
typedef __attribute__((ext_vector_type(4))) unsigned int uint4v;

#define C_CH   256
#define HW_IMG 3136
#define CHW    802816     // 256*3136
#define WELEM  589824     // 256*2304
#define WROWS  192        // staged window rows
#define RSTR   40         // LDS row stride in ushorts (32 data + 8 pad) = 80B
#define BUFE   7680       // WROWS*RSTR ushorts per buffer (15360B)
#define NCH    8          // ci chunks of 32
#define NSTEP  72         // 8 chunks * 9 taps

__device__ __forceinline__ ushort f2bf(float f){
    union{__hip_bfloat16 h; ushort u;} c; c.h = __float2bfloat16(f); return c.u;
}

__global__ __launch_bounds__(256) void prep_kernel(
    const float* __restrict__ w1, const float* __restrict__ w2,
    const float* __restrict__ g1, const float* __restrict__ b1,
    const float* __restrict__ m1, const float* __restrict__ v1,
    const float* __restrict__ g2, const float* __restrict__ b2,
    const float* __restrict__ m2, const float* __restrict__ v2,
    ushort* __restrict__ wf1, ushort* __restrict__ wf2,
    float* __restrict__ bn, ushort* __restrict__ zb)
{
    int gid = blockIdx.x * 256 + threadIdx.x;
    // frag-packed: d = (((c*9+r)*16 + ct)*64 + l)*8 + j
    // co = ct*16 + (l&15), ci = c*32 + (l>>4)*8 + j, tap r
    if (gid < WELEM) {
        int j = gid & 7, l = (gid >> 3) & 63, ct = (gid >> 9) & 15, rr = gid >> 13;
        int c = rr / 9, r = rr - c * 9;
        int co = ct * 16 + (l & 15);
        int ci = c * 32 + (l >> 4) * 8 + j;
        wf1[gid] = f2bf(w1[(co * C_CH + ci) * 9 + r]);
    }
    int g2i = gid - WELEM;
    if (g2i >= 0 && g2i < WELEM) {
        int j = g2i & 7, l = (g2i >> 3) & 63, ct = (g2i >> 9) & 15, rr = g2i >> 13;
        int c = rr / 9, r = rr - c * 9;
        int co = ct * 16 + (l & 15);
        int ci = c * 32 + (l >> 4) * 8 + j;
        wf2[g2i] = f2bf(w2[(co * C_CH + ci) * 9 + r]);
    }
    if (gid < C_CH) {
        float i1 = g1[gid] * rsqrtf(v1[gid] + 1e-5f);
        bn[gid]            = i1;
        bn[C_CH + gid]     = b1[gid] - m1[gid] * i1;
        float i2 = g2[gid] * rsqrtf(v2[gid] + 1e-5f);
        bn[2*C_CH + gid]   = i2;
        bn[3*C_CH + gid]   = b2[gid] - m2[gid] * i2;
    }
    if (gid < 512) zb[gid] = 0;
}

// x [n][ci][p] f32 -> xT [n][p][ci] bf16
__global__ __launch_bounds__(256) void xpose_kernel(
    const float* __restrict__ x, ushort* __restrict__ xT)
{
    __shared__ ushort T[64 * 72];
    int tid = threadIdx.x;
    int b = blockIdx.x;                  // 32*49*4
    int n = b / 196, rem = b % 196;
    int pb = rem >> 2, cb = rem & 3;
    int lane = tid & 63, cr = tid >> 6;
    const float* xp = x + ((size_t)(n * C_CH + cb * 64)) * HW_IMG + pb * 64 + lane;
#pragma unroll
    for (int j = 0; j < 16; ++j) {
        int cil = cr * 16 + j;
        T[lane * 72 + cil] = f2bf(xp[(size_t)cil * HW_IMG]);
    }
    __syncthreads();
#pragma unroll
    for (int it = 0; it < 2; ++it) {
        int slot = it * 256 + tid;       // 512 slots = 64 rows x 8 granules
        int p = slot >> 3, g = slot & 7;
        uint4v v = *(const uint4v*)&T[p * 72 + g * 8];
        *(uint4v*)(xT + ((size_t)n * HW_IMG + pb * 64 + p) * C_CH + cb * 64 + g * 8) = v;
    }
}

template<bool SECOND>
__global__ __launch_bounds__(256, 2) void conv_kernel(
    const ushort* __restrict__ srcT,    // [n][p][ci] bf16
    const ushort* __restrict__ wf,      // frag-packed weights
    const float* __restrict__ bnp,      // inv | add
    const float* __restrict__ ident,    // x fp32 (conv2)
    const ushort* __restrict__ zb,
    void* __restrict__ dst)
{
    // window dbuf 2*15360B; conv1 epilogue reuses as 64x264 transpose (33792B)
    __shared__ ushort B[16896];

    const int tid = threadIdx.x;
    const int wv = tid >> 6, l = tid & 63;
    const int lr = l & 15, lg = l >> 4;

    int bid = blockIdx.x;
    int swz = (bid & 7) * 196 + (bid >> 3);   // XCD-chunked, bijective (1568=8*196)
    const int n = swz / 49, pt = swz % 49;
    const int p0 = pt * 64;

    // W-border masks per nc (lane's output p = p0 + nc*16 + lr)
    bool wLa[4], wRa[4];
    int vbe[4];
#pragma unroll
    for (int nc = 0; nc < 4; ++nc) {
        int p = p0 + nc * 16 + lr;
        int w = p % 56;
        wLa[nc] = (w > 0);
        wRa[nc] = (w < 55);
        vbe[nc] = (64 + nc * 16 + lr) * RSTR + lg * 8;   // B-frag LDS base (ushort)
    }

    // staging: 960 slots of 16B per chunk; slot = round*256+tid; dest linear.
    // slot -> row=slot/5, g=slot%5 (g==4 is pad -> zb)
    const ushort* sA[4];
#pragma unroll
    for (int rd = 0; rd < 4; ++rd) {
        int slot = rd * 256 + tid;
        int row = slot / 5, g = slot - row * 5;
        int gp = p0 - 64 + row;
        bool val = (g < 4) && (gp >= 0) && (gp < HW_IMG) && (slot < 960);
        sA[rd] = val ? (srcT + ((size_t)n * HW_IMG + gp) * C_CH + g * 8)
                     : (zb + g * 8);
    }

    auto stage = [&](int cix, int bufE) {
#pragma unroll
        for (int rd = 0; rd < 4; ++rd) {
            if (rd < 3 || tid < 192) {
                __builtin_amdgcn_global_load_lds(
                    (const __attribute__((address_space(1))) void*)(sA[rd] + cix * 32),
                    (__attribute__((address_space(3))) void*)&B[bufE + (rd * 256 + tid) * 8],
                    16, 0, 0);
            }
        }
    };

    f32x4 acc[4][4];
#pragma unroll
    for (int mr = 0; mr < 4; ++mr)
#pragma unroll
        for (int nc = 0; nc < 4; ++nc) {
            f32x4 z = {0.f, 0.f, 0.f, 0.f};
            acc[mr][nc] = z;
        }
    const bf16x8 z8 = {0,0,0,0,0,0,0,0};

    bf16x8 areg[3][4];
    const ushort* pWb = wf + wv * 2048 + l * 8;   // + (c*9+r)*8192 + mr*512

    auto loadA = [&](int t, bf16x8* a) {          // t compile-time
#pragma unroll
        for (int mr = 0; mr < 4; ++mr)
            a[mr] = *(const bf16x8*)(pWb + t * 8192 + mr * 512);
    };

    // prologue: window chunk 0 staged, A steps 0,1 in regs
    stage(0, 0);
    loadA(0, areg[0]);
    loadA(1, areg[1]);
    __syncthreads();

#pragma unroll
    for (int c = 0; c < NCH; ++c) {
        const int bufE = (c & 1) ? BUFE : 0;
        if (c + 1 < NCH) stage(c + 1, bufE ^ BUFE);
#pragma unroll
        for (int s = 0; s < 9; ++s) {
            const int t = c * 9 + s;
            if (t + 2 < NSTEP) loadA(t + 2, areg[(t + 2) % 3]);
            const int dh = s / 3 - 1, dw = s % 3 - 1;
            const int off = dh * 56 + dw;
            bf16x8 bq[4];
#pragma unroll
            for (int nc = 0; nc < 4; ++nc) {
                bq[nc] = *(const bf16x8*)&B[vbe[nc] + bufE + off * RSTR];
                if (dw == -1) bq[nc] = wLa[nc] ? bq[nc] : z8;
                if (dw ==  1) bq[nc] = wRa[nc] ? bq[nc] : z8;
            }
#pragma unroll
            for (int mr = 0; mr < 4; ++mr)
#pragma unroll
                for (int nc = 0; nc < 4; ++nc)
                    acc[mr][nc] = __builtin_amdgcn_mfma_f32_16x16x32_bf16(
                        areg[t % 3][mr], bq[nc], acc[mr][nc], 0, 0, 0);
        }
        __syncthreads();
    }

    if constexpr (!SECOND) {
        // epilogue: BN+ReLU, LDS-transpose to yT [n][p][co] bf16
        ushort* T = B;                  // [64 p][264] (256 co + 8 pad)
#pragma unroll
        for (int mr = 0; mr < 4; ++mr) {
#pragma unroll
            for (int nc = 0; nc < 4; ++nc) {
                int co0 = wv * 64 + mr * 16 + lg * 4;
                float v0 = fmaxf(acc[mr][nc][0] * bnp[co0+0] + bnp[C_CH+co0+0], 0.f);
                float v1 = fmaxf(acc[mr][nc][1] * bnp[co0+1] + bnp[C_CH+co0+1], 0.f);
                float v2 = fmaxf(acc[mr][nc][2] * bnp[co0+2] + bnp[C_CH+co0+2], 0.f);
                float v3 = fmaxf(acc[mr][nc][3] * bnp[co0+3] + bnp[C_CH+co0+3], 0.f);
                uint2 pk;
                pk.x = (uint)f2bf(v0) | ((uint)f2bf(v1) << 16);
                pk.y = (uint)f2bf(v2) | ((uint)f2bf(v3) << 16);
                *(uint2*)&T[(nc * 16 + lr) * 264 + co0] = pk;
            }
        }
        __syncthreads();
        ushort* yT = (ushort*)dst;
#pragma unroll
        for (int it = 0; it < 8; ++it) {
            int slot = it * 256 + tid;  // 2048 slots = 64 rows x 32 granules
            int row = slot >> 5, g = slot & 31;
            uint4v v = *(const uint4v*)&T[row * 264 + g * 8];
            *(uint4v*)(yT + ((size_t)n * HW_IMG + p0 + row) * C_CH + g * 8) = v;
        }
    } else {
        // epilogue: BN + identity + ReLU, fp32 out [n][co][p]
        const size_t nbase = (size_t)n * CHW;
        float* out = (float*)dst;
#pragma unroll
        for (int mr = 0; mr < 4; ++mr) {
#pragma unroll
            for (int nc = 0; nc < 4; ++nc) {
                int pc = p0 + nc * 16 + lr;
#pragma unroll
                for (int i = 0; i < 4; ++i) {
                    int co = wv * 64 + mr * 16 + lg * 4 + i;
                    size_t o = nbase + (size_t)co * HW_IMG + pc;
                    float val = acc[mr][nc][i] * bnp[co] + bnp[C_CH + co] + ident[o];
                    out[o] = fmaxf(val, 0.f);
                }
            }
        }
    }
}

extern "C" void kernel_launch(void* const* d_in, const int* in_sizes, int n_in,
                              void* d_out, int out_size, void* d_ws, size_t ws_size,
                              hipStream_t stream) {
    const float* x  = (const float*)d_in[0];
    const float* w1 = (const float*)d_in[1];
    const float* g1 = (const float*)d_in[2];
    const float* b1 = (const float*)d_in[3];
    const float* m1 = (const float*)d_in[4];
    const float* v1 = (const float*)d_in[5];
    const float* w2 = (const float*)d_in[6];
    const float* g2 = (const float*)d_in[7];
    const float* b2 = (const float*)d_in[8];
    const float* m2 = (const float*)d_in[9];
    const float* v2 = (const float*)d_in[10];

    ushort* wf1 = (ushort*)d_ws;
    ushort* wf2 = wf1 + WELEM;
    float*  bn  = (float*)(wf2 + WELEM);
    ushort* zb  = (ushort*)(bn + 4 * C_CH);
    ushort* yT  = zb + 512;
    ushort* xT  = (ushort*)d_out;   // scratch in d_out; conv2 overwrites fully

    prep_kernel<<<dim3(4608), dim3(256), 0, stream>>>(
        w1, w2, g1, b1, m1, v1, g2, b2, m2, v2, wf1, wf2, bn, zb);

    xpose_kernel<<<dim3(6272), dim3(256), 0, stream>>>(x, xT);

    conv_kernel<false><<<dim3(1568), dim3(256), 0, stream>>>(
        xT, wf1, bn, x, zb, (void*)yT);

    conv_kernel<true><<<dim3(1568), dim3(256), 0, stream>>>(
        yT, wf2, bn + 512, x, zb, d_out);
}

// Round 5
// 263.176 us; speedup vs baseline: 3.2957x; 1.4516x over previous
//
#include <hip/hip_runtime.h>
#include <hip/hip_bf16.h>

// BasicBlock via chunked shift-GEMM bf16 MFMA. R4: decouple vmcnt chains
// (stage issued MID-chunk so A-frag waits never drain fresh HBM stage
// loads), T5 setprio around MFMA clusters, launch_bounds(256,3).
// Structure: output tile 256co x 64p; ci in 8 chunks of 32. Per chunk a
// 192-row window [p0-64,p0+128) x 32ci staged to LDS via global_load_lds;
// 9 tap-steps of ds_read+MFMA; K flattened to 72 compile-time steps with
// A-frags (weights, L2/L3-resident) prefetched 2 steps ahead into a
// 3-deep static register rotation. 1 barrier per chunk.

typedef __attribute__((ext_vector_type(8))) short bf16x8;
typedef __attribute__((ext_vector_type(4))) float f32x4;
typedef __attribute__((ext_vector_type(4))) unsigned int uint4v;

#define C_CH   256
#define HW_IMG 3136
#define CHW    802816     // 256*3136
#define WELEM  589824     // 256*2304
#define WROWS  192        // staged window rows
#define RSTR   40         // LDS row stride in ushorts (32 data + 8 pad) = 80B
#define BUFE   7680       // WROWS*RSTR ushorts per buffer (15360B)
#define NCH    8          // ci chunks of 32
#define NSTEP  72         // 8 chunks * 9 taps

__device__ __forceinline__ ushort f2bf(float f){
    union{__hip_bfloat16 h; ushort u;} c; c.h = __float2bfloat16(f); return c.u;
}

__global__ __launch_bounds__(256) void prep_kernel(
    const float* __restrict__ w1, const float* __restrict__ w2,
    const float* __restrict__ g1, const float* __restrict__ b1,
    const float* __restrict__ m1, const float* __restrict__ v1,
    const float* __restrict__ g2, const float* __restrict__ b2,
    const float* __restrict__ m2, const float* __restrict__ v2,
    ushort* __restrict__ wf1, ushort* __restrict__ wf2,
    float* __restrict__ bn, ushort* __restrict__ zb)
{
    int gid = blockIdx.x * 256 + threadIdx.x;
    // frag-packed: d = (((c*9+r)*16 + ct)*64 + l)*8 + j
    // co = ct*16 + (l&15), ci = c*32 + (l>>4)*8 + j, tap r
    if (gid < WELEM) {
        int j = gid & 7, l = (gid >> 3) & 63, ct = (gid >> 9) & 15, rr = gid >> 13;
        int c = rr / 9, r = rr - c * 9;
        int co = ct * 16 + (l & 15);
        int ci = c * 32 + (l >> 4) * 8 + j;
        wf1[gid] = f2bf(w1[(co * C_CH + ci) * 9 + r]);
    }
    int g2i = gid - WELEM;
    if (g2i >= 0 && g2i < WELEM) {
        int j = g2i & 7, l = (g2i >> 3) & 63, ct = (g2i >> 9) & 15, rr = g2i >> 13;
        int c = rr / 9, r = rr - c * 9;
        int co = ct * 16 + (l & 15);
        int ci = c * 32 + (l >> 4) * 8 + j;
        wf2[g2i] = f2bf(w2[(co * C_CH + ci) * 9 + r]);
    }
    if (gid < C_CH) {
        float i1 = g1[gid] * rsqrtf(v1[gid] + 1e-5f);
        bn[gid]            = i1;
        bn[C_CH + gid]     = b1[gid] - m1[gid] * i1;
        float i2 = g2[gid] * rsqrtf(v2[gid] + 1e-5f);
        bn[2*C_CH + gid]   = i2;
        bn[3*C_CH + gid]   = b2[gid] - m2[gid] * i2;
    }
    if (gid < 512) zb[gid] = 0;
}

// x [n][ci][p] f32 -> xT [n][p][ci] bf16
__global__ __launch_bounds__(256) void xpose_kernel(
    const float* __restrict__ x, ushort* __restrict__ xT)
{
    __shared__ ushort T[64 * 72];
    int tid = threadIdx.x;
    int b = blockIdx.x;                  // 32*49*4
    int n = b / 196, rem = b % 196;
    int pb = rem >> 2, cb = rem & 3;
    int lane = tid & 63, cr = tid >> 6;
    const float* xp = x + ((size_t)(n * C_CH + cb * 64)) * HW_IMG + pb * 64 + lane;
#pragma unroll
    for (int j = 0; j < 16; ++j) {
        int cil = cr * 16 + j;
        T[lane * 72 + cil] = f2bf(xp[(size_t)cil * HW_IMG]);
    }
    __syncthreads();
#pragma unroll
    for (int it = 0; it < 2; ++it) {
        int slot = it * 256 + tid;       // 512 slots = 64 rows x 8 granules
        int p = slot >> 3, g = slot & 7;
        uint4v v = *(const uint4v*)&T[p * 72 + g * 8];
        *(uint4v*)(xT + ((size_t)n * HW_IMG + pb * 64 + p) * C_CH + cb * 64 + g * 8) = v;
    }
}

template<bool SECOND>
__global__ __launch_bounds__(256, 3) void conv_kernel(
    const ushort* __restrict__ srcT,    // [n][p][ci] bf16
    const ushort* __restrict__ wf,      // frag-packed weights
    const float* __restrict__ bnp,      // inv | add
    const float* __restrict__ ident,    // x fp32 (conv2)
    const ushort* __restrict__ zb,
    void* __restrict__ dst)
{
    // window dbuf 2*15360B; conv1 epilogue reuses as 64x264 transpose (33792B)
    __shared__ ushort B[16896];

    const int tid = threadIdx.x;
    const int wv = tid >> 6, l = tid & 63;
    const int lr = l & 15, lg = l >> 4;

    int bid = blockIdx.x;
    int swz = (bid & 7) * 196 + (bid >> 3);   // XCD-chunked, bijective (1568=8*196)
    const int n = swz / 49, pt = swz % 49;
    const int p0 = pt * 64;

    // W-border masks per nc (lane's output p = p0 + nc*16 + lr)
    bool wLa[4], wRa[4];
    int vbe[4];
#pragma unroll
    for (int nc = 0; nc < 4; ++nc) {
        int p = p0 + nc * 16 + lr;
        int w = p % 56;
        wLa[nc] = (w > 0);
        wRa[nc] = (w < 55);
        vbe[nc] = (64 + nc * 16 + lr) * RSTR + lg * 8;   // B-frag LDS base (ushort)
    }

    // staging: 960 slots of 16B per chunk; slot = round*256+tid; dest linear.
    // slot -> row=slot/5, g=slot%5 (g==4 is pad -> zb)
    const ushort* sA[4];
#pragma unroll
    for (int rd = 0; rd < 4; ++rd) {
        int slot = rd * 256 + tid;
        int row = slot / 5, g = slot - row * 5;
        int gp = p0 - 64 + row;
        bool val = (g < 4) && (gp >= 0) && (gp < HW_IMG) && (slot < 960);
        sA[rd] = val ? (srcT + ((size_t)n * HW_IMG + gp) * C_CH + g * 8)
                     : (zb + g * 8);
    }

    auto stage = [&](int cix, int bufE) {
#pragma unroll
        for (int rd = 0; rd < 4; ++rd) {
            if (rd < 3 || tid < 192) {
                __builtin_amdgcn_global_load_lds(
                    (const __attribute__((address_space(1))) void*)(sA[rd] + cix * 32),
                    (__attribute__((address_space(3))) void*)&B[bufE + (rd * 256 + tid) * 8],
                    16, 0, 0);
            }
        }
    };

    f32x4 acc[4][4];
#pragma unroll
    for (int mr = 0; mr < 4; ++mr)
#pragma unroll
        for (int nc = 0; nc < 4; ++nc) {
            f32x4 z = {0.f, 0.f, 0.f, 0.f};
            acc[mr][nc] = z;
        }
    const bf16x8 z8 = {0,0,0,0,0,0,0,0};

    bf16x8 areg[3][4];
    const ushort* pWb = wf + wv * 2048 + l * 8;   // + (c*9+r)*8192 + mr*512

    auto loadA = [&](int t, bf16x8* a) {          // t compile-time
#pragma unroll
        for (int mr = 0; mr < 4; ++mr)
            a[mr] = *(const bf16x8*)(pWb + t * 8192 + mr * 512);
    };

    // prologue: window chunk 0 staged, A steps 0,1 in regs
    stage(0, 0);
    loadA(0, areg[0]);
    loadA(1, areg[1]);
    __syncthreads();

#pragma unroll
    for (int c = 0; c < NCH; ++c) {
        const int bufE = (c & 1) ? BUFE : 0;
#pragma unroll
        for (int s = 0; s < 9; ++s) {
            const int t = c * 9 + s;
            if (t + 2 < NSTEP) loadA(t + 2, areg[(t + 2) % 3]);
            // stage NEXT chunk mid-chunk: after this step's A-load so that
            // steps s..s+1 A-waits (older than stage) don't drain it, and
            // it lands ~6 steps before the end-of-chunk barrier needs it.
            if (s == 3 && c + 1 < NCH) stage(c + 1, bufE ^ BUFE);
            const int dh = s / 3 - 1, dw = s % 3 - 1;
            const int off = dh * 56 + dw;
            bf16x8 bq[4];
#pragma unroll
            for (int nc = 0; nc < 4; ++nc) {
                bq[nc] = *(const bf16x8*)&B[vbe[nc] + bufE + off * RSTR];
                if (dw == -1) bq[nc] = wLa[nc] ? bq[nc] : z8;
                if (dw ==  1) bq[nc] = wRa[nc] ? bq[nc] : z8;
            }
            __builtin_amdgcn_s_setprio(1);
#pragma unroll
            for (int mr = 0; mr < 4; ++mr)
#pragma unroll
                for (int nc = 0; nc < 4; ++nc)
                    acc[mr][nc] = __builtin_amdgcn_mfma_f32_16x16x32_bf16(
                        areg[t % 3][mr], bq[nc], acc[mr][nc], 0, 0, 0);
            __builtin_amdgcn_s_setprio(0);
        }
        __syncthreads();
    }

    if constexpr (!SECOND) {
        // epilogue: BN+ReLU, LDS-transpose to yT [n][p][co] bf16
        ushort* T = B;                  // [64 p][264] (256 co + 8 pad)
#pragma unroll
        for (int mr = 0; mr < 4; ++mr) {
#pragma unroll
            for (int nc = 0; nc < 4; ++nc) {
                int co0 = wv * 64 + mr * 16 + lg * 4;
                float v0 = fmaxf(acc[mr][nc][0] * bnp[co0+0] + bnp[C_CH+co0+0], 0.f);
                float v1 = fmaxf(acc[mr][nc][1] * bnp[co0+1] + bnp[C_CH+co0+1], 0.f);
                float v2 = fmaxf(acc[mr][nc][2] * bnp[co0+2] + bnp[C_CH+co0+2], 0.f);
                float v3 = fmaxf(acc[mr][nc][3] * bnp[co0+3] + bnp[C_CH+co0+3], 0.f);
                uint2 pk;
                pk.x = (uint)f2bf(v0) | ((uint)f2bf(v1) << 16);
                pk.y = (uint)f2bf(v2) | ((uint)f2bf(v3) << 16);
                *(uint2*)&T[(nc * 16 + lr) * 264 + co0] = pk;
            }
        }
        __syncthreads();
        ushort* yT = (ushort*)dst;
#pragma unroll
        for (int it = 0; it < 8; ++it) {
            int slot = it * 256 + tid;  // 2048 slots = 64 rows x 32 granules
            int row = slot >> 5, g = slot & 31;
            uint4v v = *(const uint4v*)&T[row * 264 + g * 8];
            *(uint4v*)(yT + ((size_t)n * HW_IMG + p0 + row) * C_CH + g * 8) = v;
        }
    } else {
        // epilogue: BN + identity + ReLU, fp32 out [n][co][p]
        const size_t nbase = (size_t)n * CHW;
        float* out = (float*)dst;
#pragma unroll
        for (int mr = 0; mr < 4; ++mr) {
#pragma unroll
            for (int nc = 0; nc < 4; ++nc) {
                int pc = p0 + nc * 16 + lr;
#pragma unroll
                for (int i = 0; i < 4; ++i) {
                    int co = wv * 64 + mr * 16 + lg * 4 + i;
                    size_t o = nbase + (size_t)co * HW_IMG + pc;
                    float val = acc[mr][nc][i] * bnp[co] + bnp[C_CH + co] + ident[o];
                    out[o] = fmaxf(val, 0.f);
                }
            }
        }
    }
}

extern "C" void kernel_launch(void* const* d_in, const int* in_sizes, int n_in,
                              void* d_out, int out_size, void* d_ws, size_t ws_size,
                              hipStream_t stream) {
    const float* x  = (const float*)d_in[0];
    const float* w1 = (const float*)d_in[1];
    const float* g1 = (const float*)d_in[2];
    const float* b1 = (const float*)d_in[3];
    const float* m1 = (const float*)d_in[4];
    const float* v1 = (const float*)d_in[5];
    const float* w2 = (const float*)d_in[6];
    const float* g2 = (const float*)d_in[7];
    const float* b2 = (const float*)d_in[8];
    const float* m2 = (const float*)d_in[9];
    const float* v2 = (const float*)d_in[10];

    ushort* wf1 = (ushort*)d_ws;
    ushort* wf2 = wf1 + WELEM;
    float*  bn  = (float*)(wf2 + WELEM);
    ushort* zb  = (ushort*)(bn + 4 * C_CH);
    ushort* yT  = zb + 512;
    ushort* xT  = (ushort*)d_out;   // scratch in d_out; conv2 overwrites fully

    prep_kernel<<<dim3(4608), dim3(256), 0, stream>>>(
        w1, w2, g1, b1, m1, v1, g2, b2, m2, v2, wf1, wf2, bn, zb);

    xpose_kernel<<<dim3(6272), dim3(256), 0, stream>>>(x, xT);

    conv_kernel<false><<<dim3(1568), dim3(256), 0, stream>>>(
        xT, wf1, bn, x, zb, (void*)yT);

    conv_kernel<true><<<dim3(1568), dim3(256), 0, stream>>>(
        yT, wf2, bn + 512, x, zb, d_out);
}